// Round 12
// baseline (58.124 us; speedup 1.0000x reference)
//
#include <hip/hip_runtime.h>
#include <math.h>

#define BB 32
#define TT 8192
#define CCH 128
#define OO 64
#define DD 288
#define NFREQ 12
#define NIJ 144

typedef _Float16 v8h __attribute__((ext_vector_type(8)));
typedef float f32x4 __attribute__((ext_vector_type(4)));

// ---------------- K1f: fourier emb + scores + softmax -> fragH, fused ----------------
#define IJ_CHUNK 36
#define EMB_LD 129

__global__ __launch_bounds__(256) void k1f_frag(const float* __restrict__ pos,
                                                const float* __restrict__ heads,
                                                uint4* __restrict__ fragH) {
    __shared__ float smem[2 * IJ_CHUNK * EMB_LD];   // 9288 floats = 37 KB
    float* cos_s = smem;
    float* sin_s = smem + IJ_CHUNK * EMB_LD;

    const int b = blockIdx.x;
    const int oy = blockIdx.y;            // == ot of the fragment
    const int obase = oy * 16;
    const int tid = threadIdx.x;
    const int c = tid & 127;
    const int hh = __builtin_amdgcn_readfirstlane(tid >> 7);  // wave-uniform

    const float* posb = pos + b * CCH * 2;
    const float S = 4.487989505128276f;  // 2*pi/1.4

    float accs[8];
#pragma unroll
    for (int k = 0; k < 8; ++k) accs[k] = 0.f;

#pragma unroll 1
    for (int cc = 0; cc < NIJ; cc += IJ_CHUNK) {
#pragma unroll 1
        for (int it = 0; it < (IJ_CHUNK * CCH) / 256; ++it) {
            int idx = it * 256 + tid;
            int ec = idx & 127;
            int ijl = idx >> 7;
            int ij = cc + ijl;
            int i = ij / NFREQ;
            int j = ij - i * NFREQ;
            float px = posb[2 * ec] + 0.2f;
            float py = posb[2 * ec + 1] + 0.2f;
            float ang = px * (S * (float)i) + py * (S * (float)j);
            float sv, cv;
            __sincosf(ang, &sv, &cv);
            cos_s[ijl * EMB_LD + ec] = cv;
            sin_s[ijl * EMB_LD + ec] = sv;
        }
        __syncthreads();
#pragma unroll 4
        for (int ijl = 0; ijl < IJ_CHUNK; ++ijl) {
            float cv = cos_s[ijl * EMB_LD + c];
            float sv = sin_s[ijl * EMB_LD + c];
            const float* hrow = heads + (size_t)(obase + hh * 8) * DD + (cc + ijl);
#pragma unroll
            for (int k = 0; k < 8; ++k) {
                accs[k] = fmaf(cv, hrow[k * DD], fmaf(sv, hrow[k * DD + NIJ], accs[k]));
            }
        }
        __syncthreads();
    }

    // scores -> LDS [16][129]
    float* sc = smem;
#pragma unroll
    for (int k = 0; k < 8; ++k) {
        sc[(hh * 8 + k) * EMB_LD + c] = accs[k];
    }
    __syncthreads();

    float* red  = smem + 16 * EMB_LD;
    float* red2 = red + 256;
    const int o16 = tid >> 4;
    const int part = tid & 15;
    const float* srow = sc + o16 * EMB_LD + part * 8;

    float m = -1e30f;
#pragma unroll
    for (int j = 0; j < 8; ++j) m = fmaxf(m, srow[j]);
    red[o16 * 16 + part] = m;
    __syncthreads();
    float M = red[o16 * 16];
#pragma unroll
    for (int p = 1; p < 16; ++p) M = fmaxf(M, red[o16 * 16 + p]);

    float ev[8];
    float s = 0.f;
#pragma unroll
    for (int j = 0; j < 8; ++j) { ev[j] = __expf(srow[j] - M); s += ev[j]; }
    red2[o16 * 16 + part] = s;
    __syncthreads();
    float Sum = 0.f;
#pragma unroll
    for (int p = 0; p < 16; ++p) Sum += red2[o16 * 16 + p];
    float inv = 1.f / Sum;

    v8h h;
#pragma unroll
    for (int j = 0; j < 8; ++j) h[j] = (_Float16)(ev[j] * inv);
    union { uint4 u; v8h v; } u;
    u.v = h;
    const int kc = part >> 2;
    const int lane = (part & 3) * 16 + o16;
    fragH[((b * 4 + kc) * 4 + oy) * 64 + lane] = u.u;
}

// ---------------- K2: persistent-wave pipeline, DENSE reads AND writes ----------------
// 512 blocks x 4 waves; wave owns 128 t-rows of one b (8 tiles of 16 rows).
// Reads:  global_load_lds 16B, per-instr = 2 rows x 512B line-dense; source
//         granule pre-swizzled (g ^= row&7) so frag ds_read_b128 is ~2-way.
// Writes: MFMA acc -> ds_write_b128 into the just-consumed buffer (overlay;
//         DS ops are per-wave in-order so WAR on the buffer is safe), XOR-
//         swizzled granules, then 4x ds_read_b128 + 4x fully-SEQUENTIAL 1KB
//         global_store_dwordx4 per tile (out rows are 256B; 4 rows/instr).
// vmcnt counts stores on gfx9: steady-state wait = vmcnt(12) (= 4 stores of
// tile i-1 + 8 loads of tile i+1 in flight; never drains to 0 in the loop).
// RULE #20: all acc/bw indices compile-time. RULE #18: sched_barrier around
// asm waits. RULE #21: stage-source and ds-read use the same involution.
__device__ __forceinline__ void load_lds16(const float* g, float* l) {
    __builtin_amdgcn_global_load_lds(
        (const __attribute__((address_space(1))) unsigned int*)g,
        (__attribute__((address_space(3))) unsigned int*)l,
        16, 0, 0);
}

#define OSTRIDE 68   // floats per obuf row: 16B-aligned, +XOR keeps conflicts ~2-4 way

__global__ __launch_bounds__(256) void k2_mfma(const float* __restrict__ eeg,
                                               const uint4* __restrict__ fragH,
                                               float* __restrict__ out) {
    __shared__ float lds[4][2][2048];   // per wave: 2 bufs x 8KB = 16 KB
    const int lane = threadIdx.x & 63;
    const int wv = __builtin_amdgcn_readfirstlane(threadIdx.x >> 6);
    const int wgid = blockIdx.x * 4 + wv;
    const int b = wgid >> 6;        // 64 waves per b
    const int chunk = wgid & 63;    // 128-row chunk within b
    const int r16 = lane & 15;
    const int q = lane >> 4;

    // w-fragments for this b: 64 VGPR, loaded once (L2-hot)
    v8h bw[4][4];
    {
        const uint4* fp = fragH + (size_t)(b * 16) * 64 + lane;
#pragma unroll
        for (int kc = 0; kc < 4; ++kc)
#pragma unroll
            for (int ot = 0; ot < 4; ++ot) {
                union { uint4 u; v8h v; } u;
                u.u = fp[(kc * 4 + ot) * 64];
                bw[kc][ot] = u.v;
            }
    }

    const float* slice = eeg + ((size_t)b * TT + chunk * 128) * CCH;   // 64 KB
    float4* ob4 = (float4*)(out + ((size_t)b * TT + chunk * 128) * OO);

#define STAGE(tile, buf)                                                        \
    {                                                                           \
        const float* tsrc = slice + (size_t)(tile) * 16 * CCH;                  \
        float* dst = &lds[wv][buf][0];                                          \
        _Pragma("unroll")                                                       \
        for (int s = 0; s < 8; ++s) {                                           \
            int G = s * 64 + lane;      /* 16B-granule idx in 8KB tile */       \
            int r = G >> 5;             /* row 0..15 */                         \
            int g = G & 31;                                                     \
            int gs = g ^ (r & 7);       /* pre-swizzled source granule */       \
            load_lds16(tsrc + r * CCH + gs * 4, dst + s * 256);                 \
        }                                                                       \
    }

#define CONSUME(tile, buf)                                                      \
    {                                                                           \
        float* lb = &lds[wv][buf][0];                                           \
        f32x4 acc[4];                                                           \
        _Pragma("unroll")                                                       \
        for (int ot = 0; ot < 4; ++ot) acc[ot] = (f32x4){0.f, 0.f, 0.f, 0.f};   \
        _Pragma("unroll")                                                       \
        for (int kc = 0; kc < 4; ++kc) {                                        \
            int g0 = kc * 8 + q * 2;                                            \
            float4 e0 = *(const float4*)(lb + r16 * 128 + ((g0 ^ (r16 & 7)) * 4));        \
            float4 e1 = *(const float4*)(lb + r16 * 128 + (((g0 + 1) ^ (r16 & 7)) * 4));  \
            v8h eh;                                                             \
            eh[0] = (_Float16)e0.x; eh[1] = (_Float16)e0.y;                     \
            eh[2] = (_Float16)e0.z; eh[3] = (_Float16)e0.w;                     \
            eh[4] = (_Float16)e1.x; eh[5] = (_Float16)e1.y;                     \
            eh[6] = (_Float16)e1.z; eh[7] = (_Float16)e1.w;                     \
            _Pragma("unroll")                                                   \
            for (int ot = 0; ot < 4; ++ot)                                      \
                acc[ot] = __builtin_amdgcn_mfma_f32_16x16x32_f16(bw[kc][ot], eh, acc[ot], 0, 0, 0); \
        }                                                                       \
        /* transpose: lane holds D[o=ot*16+q*4+reg][t=r16]; logical obuf[t][o] */ \
        _Pragma("unroll")                                                       \
        for (int ot = 0; ot < 4; ++ot) {                                        \
            int go = ot * 4 + q;            /* logical float4-granule in row */ \
            int gs = go ^ (r16 & 7);                                            \
            *(f32x4*)(lb + r16 * OSTRIDE + gs * 4) = acc[ot];                   \
        }                                                                       \
        /* dense stores: 4 x 1KB sequential (covers 16 rows x 256B) */          \
        _Pragma("unroll")                                                       \
        for (int s = 0; s < 4; ++s) {                                           \
            int F = s * 64 + lane;          /* float4 index in 4KB out-tile */  \
            int row = F >> 4;                                                   \
            int go = F & 15;                                                    \
            int gs = go ^ (row & 7);                                            \
            float4 v = *(const float4*)(lb + row * OSTRIDE + gs * 4);           \
            ob4[(size_t)(tile) * 256 + F] = v;                                  \
        }                                                                       \
    }

    STAGE(0, 0);

#pragma unroll 1
    for (int i = 0; i < 7; ++i) {
        STAGE(i + 1, (i + 1) & 1);
        __builtin_amdgcn_sched_barrier(0);
        if (i == 0) {
            asm volatile("s_waitcnt vmcnt(8)" ::: "memory");    // L0 done; L1 in flight
        } else {
            asm volatile("s_waitcnt vmcnt(12)" ::: "memory");   // L(i) done; S(i-1)+L(i+1) fly
        }
        __builtin_amdgcn_sched_barrier(0);
        CONSUME(i, i & 1);
    }
    __builtin_amdgcn_sched_barrier(0);
    asm volatile("s_waitcnt vmcnt(0)" ::: "memory");            // drain L7 (+S6)
    __builtin_amdgcn_sched_barrier(0);
    CONSUME(7, 1);
#undef STAGE
#undef CONSUME
}

extern "C" void kernel_launch(void* const* d_in, const int* in_sizes, int n_in,
                              void* d_out, int out_size, void* d_ws, size_t ws_size,
                              hipStream_t stream) {
    const float* eeg   = (const float*)d_in[0];   // [B,T,C]
    const float* pos   = (const float*)d_in[1];   // [B,C,2]
    const float* heads = (const float*)d_in[2];   // [O,D]
    float* out = (float*)d_out;                   // [B,T,O]

    uint4* fragH = (uint4*)d_ws;                  // 32*4*4*64*16 = 524288 B

    k1f_frag<<<dim3(BB, 4), 256, 0, stream>>>(pos, heads, fragH);
    k2_mfma<<<512, 256, 0, stream>>>(eeg, fragH, out);
}